// Round 8
// baseline (3203.925 us; speedup 1.0000x reference)
//
#include <hip/hip_runtime.h>
#include <cmath>

typedef __attribute__((ext_vector_type(4))) float f32x4;
typedef __attribute__((ext_vector_type(8))) short bf16x8;

// matrices are full 256x256 fp32 squares, strict upper zeroed
#define MSZ 65536

__device__ __forceinline__ unsigned short f2bf(float f){
  unsigned u = __float_as_uint(f);
  unsigned r = (u + 0x7FFFu + ((u >> 16) & 1u)) >> 16;
  return (unsigned short)r;
}

__global__ void k_sentinel(float* __restrict__ out){ out[0] = 123456.0f; }

// ---------------- K0: partition batch indices by label ----------------
__global__ void k0_partition(const int* __restrict__ lab, int* __restrict__ cnt, int* __restrict__ idx){
  __shared__ int lcnt0[8], lcnt1[8];
  int t = threadIdx.x;              // 512 threads, 8 waves
  int w = t >> 6, lane = t & 63;
  int l = lab[t];
  unsigned long long m0 = __ballot(l == 0);
  unsigned long long bm = (lane == 0) ? 0ull : ((1ull << lane) - 1ull);
  int r0 = __popcll(m0 & bm);
  int r1 = __popcll((~m0) & bm);
  if (lane == 0){ lcnt0[w] = __popcll(m0); lcnt1[w] = 64 - __popcll(m0); }
  __syncthreads();
  int base0 = 0, base1 = 0, n0 = 0;
  #pragma unroll
  for (int i = 0; i < 8; ++i){
    if (i < w){ base0 += lcnt0[i]; base1 += lcnt1[i]; }
    n0 += lcnt0[i];
  }
  int pos = (l == 0) ? (base0 + r0) : (n0 + base1 + r1);
  idx[pos] = t;
  if (t == 0){ cnt[0] = n0; cnt[1] = 512 - n0; }
}

// ---------------- K1: per-label means ----------------
__global__ __launch_bounds__(1024) void k1_means(const float* __restrict__ x, const int* __restrict__ lab,
                                                 const int* __restrict__ cnt, float* __restrict__ means){
  __shared__ int labs[512];
  __shared__ float part[8][256];
  int t = threadIdx.x, c = blockIdx.x;
  if (t < 512) labs[t] = lab[t];
  __syncthreads();
  int k = t & 255, bq = t >> 8;
  float s0 = 0.f, s1 = 0.f;
  const float* xc = x + (size_t)c * 256 + k;
  for (int b = bq; b < 512; b += 4){
    float v = xc[(size_t)b * 65536];
    if (labs[b] == 0) s0 += v; else s1 += v;
  }
  part[bq*2+0][k] = s0;
  part[bq*2+1][k] = s1;
  __syncthreads();
  if (t < 256){
    float m0 = part[0][t] + part[2][t] + part[4][t] + part[6][t];
    float m1 = part[1][t] + part[3][t] + part[5][t] + part[7][t];
    float n0 = (float)cnt[0], n1 = (float)cnt[1];
    means[(size_t)c * 256 + t]         = m0 / fmaxf(n0, 1.f);
    means[(size_t)(256 + c) * 256 + t] = m1 / fmaxf(n1, 1.f);
  }
}

// ---------------- K2: per-(channel,label) Gram via MFMA -> Sigma full square, upper zeroed ----------------
__global__ __launch_bounds__(512) void k2_gram(const float* __restrict__ x, const float* __restrict__ cov,
    const float* __restrict__ means, const int* __restrict__ cnt, const int* __restrict__ idx,
    float* __restrict__ sig, int c0){
  __shared__ uint4 XT4[1280];      // 256 k-rows x (4 uint4 data + 1 pad uint4)
  __shared__ float mlds[256];
  int t = threadIdx.x;
  int bid = blockIdx.x;
  int l = bid & 1, c = c0 + (bid >> 1);
  int n0 = cnt[0], n1 = cnt[1];
  int n = l ? n1 : n0;
  int start = l ? n0 : 0;
  if (t < 256) mlds[t] = means[(size_t)(l * 256 + c) * 256 + t];

  f32x4 acc[8][4];
  #pragma unroll
  for (int i = 0; i < 8; ++i)
    #pragma unroll
    for (int jn = 0; jn < 4; ++jn){ f32x4 z; z.x = 0.f; z.y = 0.f; z.z = 0.f; z.w = 0.f; acc[i][jn] = z; }

  int lane = t & 63, wav = t >> 6;
  int wr = wav >> 2, wc = wav & 3;
  int lrow = lane & 15, lhalf = lane >> 4;   // lhalf in [0,4)
  int kq = t & 255, bh = t >> 8;
  int nst = (n + 31) >> 5;

  for (int s = 0; s < nst; ++s){
    __syncthreads();
    unsigned pk[8];
    #pragma unroll
    for (int m = 0; m < 8; ++m){
      int b0 = s * 32 + bh * 16 + 2 * m;
      float v0 = 0.f, v1 = 0.f;
      if (b0 < n)     v0 = x[((size_t)idx[start + b0] * 256 + c) * 256 + kq];
      if (b0 + 1 < n) v1 = x[((size_t)idx[start + b0 + 1] * 256 + c) * 256 + kq];
      pk[m] = (unsigned)f2bf(v0) | ((unsigned)f2bf(v1) << 16);
    }
    XT4[kq * 5 + bh * 2 + 0] = make_uint4(pk[0], pk[1], pk[2], pk[3]);
    XT4[kq * 5 + bh * 2 + 1] = make_uint4(pk[4], pk[5], pk[6], pk[7]);
    __syncthreads();
    bf16x8 af[8], bfr[4];
    #pragma unroll
    for (int i = 0; i < 8; ++i){
      int T = wr * 8 + i;
      af[i] = *reinterpret_cast<const bf16x8*>(&XT4[(T * 16 + lrow) * 5 + lhalf]);
    }
    #pragma unroll
    for (int jn = 0; jn < 4; ++jn){
      int T = wc * 4 + jn;
      bfr[jn] = *reinterpret_cast<const bf16x8*>(&XT4[(T * 16 + lrow) * 5 + lhalf]);
    }
    #pragma unroll
    for (int i = 0; i < 8; ++i)
      #pragma unroll
      for (int jn = 0; jn < 4; ++jn)
        acc[i][jn] = __builtin_amdgcn_mfma_f32_16x16x32_bf16(af[i], bfr[jn], acc[i][jn], 0, 0, 0);
  }
  __syncthreads();

  float invn = 1.0f / fmaxf((float)n, 1.0f);
  float* sigm = sig + (size_t)bid * MSZ;
  #pragma unroll
  for (int i = 0; i < 8; ++i){
    int Rb = (wr * 8 + i) * 16 + lhalf * 4;
    #pragma unroll
    for (int jn = 0; jn < 4; ++jn){
      int Cc = (wc * 4 + jn) * 16 + lrow;
      #pragma unroll
      for (int r = 0; r < 4; ++r){
        int R = Rb + r;
        float v = acc[i][jn][r] * invn + cov[R * 256 + Cc] - mlds[R] * mlds[Cc];
        sigm[R * 256 + Cc] = (Cc <= R) ? v : 0.0f;   // zero strict upper
      }
    }
  }
}

// ---------------- K3a: register-resident Cholesky; GEMM panel via inv(L_d) ----------------
// r6 geometry (1056 4x8 tiles, 3 slots/thread, 512 thr, (512,2) -- proven no-spill)
// + r7 algorithm (invert diag block; panel solve = parallel GEMM, no serial TRSM).
// Per 32-col step: A: stage panel tiles -> Pa (below diag) / Dd (diag);
// B: wave0 chol(Dd) + Linv -> Ld[p][j]=Linv[j][p] dense;
// C1: panel tiles W = A*Linv^T into acc (reads Pa); diag tiles refresh from Dd;
// C2: write W back into Pa (in-place A->W); D: trailing rank-32 update from Pa rows.
__global__ __launch_bounds__(512, 2) void k3a_chol(float* __restrict__ sig, float* __restrict__ logdet, int c0){
  __shared__ float Pa[224 * 36];    // 32256 B: panel rows j0+32..255, stride 36 (f32x4-aligned, 4-bank skew)
  __shared__ float Dd[32 * 33];     // 4224 B: diag block, chol L in lower
  __shared__ float Ld[32 * 36];     // 4608 B: Ld[p][j] = Linv[j][p], dense (zeros for p > j)
  int t = threadIdx.x;
  int bid = blockIdx.x;
  int l = bid & 1, c = c0 + (bid >> 1);
  float* A = sig + (size_t)bid * MSZ;

  // ---- decode slots (r6-verified) and load 4x8 tiles from global Sigma
  int Rs[3], Cs[3]; bool val[3];
  float acc[3][32];
  #pragma unroll
  for (int s = 0; s < 3; ++s){
    int i = t + 512 * s;
    val[s] = (i < 1056);
    int ii = val[s] ? i : 0;
    int m = (int)sqrtf((float)ii);
    while ((m + 1) * (m + 1) <= ii) ++m;
    while (m * m > ii) --m;
    int Rv, Cv;
    if (ii >= m * m + m){ Rv = 2 * m;     Cv = ii - m * m - m; }
    else                { Rv = 2 * m - 1; Cv = ii - m * m; }
    Rs[s] = Rv; Cs[s] = Cv;
    #pragma unroll
    for (int i4 = 0; i4 < 4; ++i4){
      if (val[s]){
        f32x4 u0 = *(const f32x4*)&A[(size_t)(4 * Rv + i4) * 256 + 8 * Cv];
        f32x4 u1 = *(const f32x4*)&A[(size_t)(4 * Rv + i4) * 256 + 8 * Cv + 4];
        acc[s][i4*8+0] = u0.x; acc[s][i4*8+1] = u0.y; acc[s][i4*8+2] = u0.z; acc[s][i4*8+3] = u0.w;
        acc[s][i4*8+4] = u1.x; acc[s][i4*8+5] = u1.y; acc[s][i4*8+6] = u1.z; acc[s][i4*8+7] = u1.w;
      } else {
        acc[s][i4*8+0] = 0.f; acc[s][i4*8+1] = 0.f; acc[s][i4*8+2] = 0.f; acc[s][i4*8+3] = 0.f;
        acc[s][i4*8+4] = 0.f; acc[s][i4*8+5] = 0.f; acc[s][i4*8+6] = 0.f; acc[s][i4*8+7] = 0.f;
      }
    }
  }

  float ldacc = 0.f;   // wave0 lane jj accumulates its own diag col
  for (int kb = 0; kb < 8; ++kb){
    int j0 = kb * 32;
    __syncthreads();   // prior step's Pa readers done
    // ---- A: stage panel-column tiles
    #pragma unroll
    for (int s = 0; s < 3; ++s){
      if (val[s] && (Cs[s] >> 2) == kb){
        int pc = 8 * (Cs[s] & 3);
        if (Rs[s] >= 8 * (kb + 1)){          // below diag -> Pa
          int rr = 4 * Rs[s] - j0 - 32;
          #pragma unroll
          for (int il = 0; il < 4; ++il){
            *(f32x4*)&Pa[(rr + il) * 36 + pc]     = *(const f32x4*)&acc[s][il*8];
            *(f32x4*)&Pa[(rr + il) * 36 + pc + 4] = *(const f32x4*)&acc[s][il*8+4];
          }
        } else {                              // diag block -> Dd
          int r0l = 4 * Rs[s] - j0;
          #pragma unroll
          for (int il = 0; il < 4; ++il)
            #pragma unroll
            for (int jl = 0; jl < 8; ++jl)
              Dd[(r0l + il) * 33 + pc + jl] = acc[s][il*8+jl];
        }
      }
    }
    __syncthreads();
    // ---- B: wave0 lockstep chol(Dd) + inversion into Ld
    if (t < 32){
      for (int jj = 0; jj < 32; ++jj){
        float dv = sqrtf(Dd[jj * 33 + jj]);
        float inv = 1.0f / dv;
        if (t == jj){ Dd[jj * 33 + jj] = dv; ldacc += logf(dv); }
        if (t > jj){
          float lv = Dd[t * 33 + jj] * inv;
          Dd[t * 33 + jj] = lv;
          for (int cq = jj + 1; cq <= t; ++cq)
            Dd[t * 33 + cq] -= lv * Dd[cq * 33 + jj];
        }
      }
      // lane j computes Linv col j -> Ld row j (Ld[j][i] = Linv[i][j])
      int j = t;
      for (int i = 0; i < j; ++i) Ld[j * 36 + i] = 0.f;
      float xjj = 1.0f / Dd[j * 33 + j];
      Ld[j * 36 + j] = xjj;
      for (int i = j + 1; i < 32; ++i){
        float s2 = Dd[i * 33 + j] * xjj;
        for (int p = j + 1; p < i; ++p)
          s2 += Dd[i * 33 + p] * Ld[j * 36 + p];
        Ld[j * 36 + i] = -s2 / Dd[i * 33 + i];
      }
    }
    __syncthreads();
    // ---- C1: panel tiles W = A * Linv^T into acc; diag tiles refresh from Dd
    #pragma unroll
    for (int s = 0; s < 3; ++s){
      if (val[s] && (Cs[s] >> 2) == kb){
        int pc = 8 * (Cs[s] & 3);
        if (Rs[s] >= 8 * (kb + 1)){
          int rr = 4 * Rs[s] - j0 - 32;
          #pragma unroll
          for (int il = 0; il < 4; ++il){
            f32x4 ar[8];
            #pragma unroll
            for (int q = 0; q < 8; ++q) ar[q] = *(const f32x4*)&Pa[(rr + il) * 36 + 4 * q];
            #pragma unroll
            for (int jl = 0; jl < 8; ++jl){
              int j = pc + jl;
              float w = 0.f;
              #pragma unroll
              for (int q = 0; q < 8; ++q){
                w += ar[q].x * Ld[(4*q+0) * 36 + j];
                w += ar[q].y * Ld[(4*q+1) * 36 + j];
                w += ar[q].z * Ld[(4*q+2) * 36 + j];
                w += ar[q].w * Ld[(4*q+3) * 36 + j];
              }
              acc[s][il*8+jl] = w;
            }
          }
        } else {
          int r0l = 4 * Rs[s] - j0;
          #pragma unroll
          for (int il = 0; il < 4; ++il)
            #pragma unroll
            for (int jl = 0; jl < 8; ++jl){
              int rg = r0l + il, cg = pc + jl;
              acc[s][il*8+jl] = (cg <= rg) ? Dd[rg * 33 + cg] : 0.f;
            }
        }
      }
    }
    __syncthreads();
    // ---- C2: write W back into Pa (in-place)
    #pragma unroll
    for (int s = 0; s < 3; ++s){
      if (val[s] && (Cs[s] >> 2) == kb && Rs[s] >= 8 * (kb + 1)){
        int pc = 8 * (Cs[s] & 3);
        int rr = 4 * Rs[s] - j0 - 32;
        #pragma unroll
        for (int il = 0; il < 4; ++il){
          *(f32x4*)&Pa[(rr + il) * 36 + pc]     = *(const f32x4*)&acc[s][il*8];
          *(f32x4*)&Pa[(rr + il) * 36 + pc + 4] = *(const f32x4*)&acc[s][il*8+4];
        }
      }
    }
    __syncthreads();
    // ---- D: trailing rank-32 update from Pa rows (f32x4 p-chunks)
    #pragma unroll
    for (int s = 0; s < 3; ++s){
      if (val[s] && (Cs[s] >> 2) > kb){
        int ar0 = 4 * Rs[s] - j0 - 32;
        int cr0 = 8 * Cs[s] - j0 - 32;
        #pragma unroll
        for (int q = 0; q < 8; ++q){
          f32x4 a0 = *(const f32x4*)&Pa[(ar0 + 0) * 36 + 4 * q];
          f32x4 a1 = *(const f32x4*)&Pa[(ar0 + 1) * 36 + 4 * q];
          f32x4 a2 = *(const f32x4*)&Pa[(ar0 + 2) * 36 + 4 * q];
          f32x4 a3 = *(const f32x4*)&Pa[(ar0 + 3) * 36 + 4 * q];
          #pragma unroll
          for (int jl = 0; jl < 8; ++jl){
            f32x4 b = *(const f32x4*)&Pa[(cr0 + jl) * 36 + 4 * q];
            acc[s][0*8+jl] -= a0.x * b.x + a0.y * b.y + a0.z * b.z + a0.w * b.w;
            acc[s][1*8+jl] -= a1.x * b.x + a1.y * b.y + a1.z * b.z + a1.w * b.w;
            acc[s][2*8+jl] -= a2.x * b.x + a2.y * b.y + a2.z * b.z + a2.w * b.w;
            acc[s][3*8+jl] -= a3.x * b.x + a3.y * b.y + a3.z * b.z + a3.w * b.w;
          }
        }
      }
    }
  }
  // ---- retire all tiles (tiles cover only the lower triangle; upper stays zero from k2)
  #pragma unroll
  for (int s = 0; s < 3; ++s){
    if (val[s]){
      #pragma unroll
      for (int il = 0; il < 4; ++il){
        f32x4 v0, v1;
        v0.x = acc[s][il*8+0]; v0.y = acc[s][il*8+1]; v0.z = acc[s][il*8+2]; v0.w = acc[s][il*8+3];
        v1.x = acc[s][il*8+4]; v1.y = acc[s][il*8+5]; v1.z = acc[s][il*8+6]; v1.w = acc[s][il*8+7];
        *(f32x4*)&A[(size_t)(4 * Rs[s] + il) * 256 + 8 * Cs[s]]     = v0;
        *(f32x4*)&A[(size_t)(4 * Rs[s] + il) * 256 + 8 * Cs[s] + 4] = v1;
      }
    }
  }
  // ---- logdet: reduce wave0 lanes
  if (t < 32){
    float v = ldacc;
    #pragma unroll
    for (int m = 1; m < 32; m <<= 1) v += __shfl_xor(v, m);
    if (t == 0) logdet[l * 256 + c] = 2.0f * v;
  }
}

// ---------------- K3b: TRSM L1 W = L0 in place, column-per-thread; trp = ||W||_F^2 ----------------
__global__ __launch_bounds__(256) void k3b_trsm(float* __restrict__ sig, float* __restrict__ trp, int c0){
  __shared__ float L1blk[32 * 256];   // 32 KB
  __shared__ float redw[4];
  int t = threadIdx.x, b = blockIdx.x;
  int lane = t & 63, wav = t >> 6;
  const float* L1 = sig + (size_t)(b * 2 + 1) * MSZ;
  float* W = sig + (size_t)(b * 2) * MSZ;     // starts as L0, becomes W
  float tracc = 0.f;

  for (int RB = 0; RB < 8; ++RB){
    int r0 = RB * 32;
    __syncthreads();
    for (int i = t; i < 32 * 256; i += 256)
      L1blk[i] = L1[(size_t)(r0 + (i >> 8)) * 256 + (i & 255)];
    __syncthreads();

    float acc[32];
    #pragma unroll
    for (int r = 0; r < 32; ++r) acc[r] = W[(size_t)(r0 + r) * 256 + t];

    for (int p = 0; p < r0; p += 8){
      float wv[8];
      #pragma unroll
      for (int q = 0; q < 8; ++q) wv[q] = W[(size_t)(p + q) * 256 + t];
      #pragma unroll
      for (int r = 0; r < 32; ++r){
        const f32x4 La = *(const f32x4*)&L1blk[r * 256 + p];
        const f32x4 Lb = *(const f32x4*)&L1blk[r * 256 + p + 4];
        acc[r] -= La.x * wv[0] + La.y * wv[1] + La.z * wv[2] + La.w * wv[3]
                + Lb.x * wv[4] + Lb.y * wv[5] + Lb.z * wv[6] + Lb.w * wv[7];
      }
    }
    // in-block forward substitution (column-private, no barriers)
    #pragma unroll
    for (int rr = 0; rr < 32; ++rr){
      float v = acc[rr];
      #pragma unroll
      for (int q = 0; q < rr; ++q)
        v -= L1blk[rr * 256 + r0 + q] * acc[q];
      v /= L1blk[rr * 256 + r0 + rr];
      acc[rr] = v;
      tracc += v * v;
      W[(size_t)(r0 + rr) * 256 + t] = v;
    }
  }
  #pragma unroll
  for (int m = 1; m < 64; m <<= 1) tracc += __shfl_xor(tracc, m);
  if (lane == 0) redw[wav] = tracc;
  __syncthreads();
  if (t == 0) trp[c0 + b] = redw[0] + redw[1] + redw[2] + redw[3];
}

// ---------------- K3c: quad = ||L1^-1 d||^2; final per-channel kl ----------------
__global__ __launch_bounds__(64) void k3c_quad(const float* __restrict__ means, const float* __restrict__ sig,
    const float* __restrict__ trp, const float* __restrict__ logdet, float* __restrict__ klp, int c0){
  __shared__ float y[256];
  int t = threadIdx.x, b = blockIdx.x;
  int c = c0 + b;
  const float* L1 = sig + (size_t)(b * 2 + 1) * MSZ;
  const float* m1p = means + (size_t)(256 + c) * 256;
  const float* m0p = means + (size_t)c * 256;

  for (int r = 0; r < 256; ++r){
    float part = 0.f;
    for (int p = t; p < r; p += 64)
      part += L1[(size_t)r * 256 + p] * y[p];
    #pragma unroll
    for (int m = 1; m < 64; m <<= 1) part += __shfl_xor(part, m);
    if (t == 0)
      y[r] = ((m1p[r] - m0p[r]) - part) / L1[(size_t)r * 256 + r];
    __syncthreads();
  }
  float q = 0.f;
  #pragma unroll
  for (int i = 0; i < 4; ++i){ float v = y[t + 64 * i]; q += v * v; }
  #pragma unroll
  for (int m = 1; m < 64; m <<= 1) q += __shfl_xor(q, m);
  if (t == 0)
    klp[c] = 0.5f * (trp[c] + q - 256.0f + logdet[256 + c] - logdet[c]);
}

// ---------------- K4: final reduce + scale ----------------
__global__ void k4_final(const float* __restrict__ klp, const int* __restrict__ cnt, float* __restrict__ out){
  __shared__ float red[256];
  int t = threadIdx.x;
  red[t] = klp[t];
  __syncthreads();
  for (int s = 128; s > 0; s >>= 1){
    if (t < s) red[t] += red[t + s];
    __syncthreads();
  }
  if (t == 0){
    float n0 = (float)cnt[0], n1 = (float)cnt[1];
    out[0] = red[0] * n0 * n1 / 256.0f / 512.0f / 512.0f;
  }
}

extern "C" void kernel_launch(void* const* d_in, const int* in_sizes, int n_in,
                              void* d_out, int out_size, void* d_ws, size_t ws_size,
                              hipStream_t stream){
  (void)in_sizes; (void)n_in; (void)out_size;
  const float* mu  = (const float*)d_in[0];
  const float* cov = (const float*)d_in[1];
  const int*   lab = (const int*)d_in[2];
  float* out = (float*)d_out;
  char* ws = (char*)d_ws;
  // ws layout (bytes):
  // means  @ 0        (524288)   trp @ 524288 (1024)   klp @ 525312 (1024)
  // logdet @ 526336   (2048)     cnt @ 528384 (8)      idx @ 528392 (2048)
  // sig    @ 1048576  (ch*2 full 256x256 fp32 squares)
  float* means  = (float*)ws;
  float* trp    = (float*)(ws + 524288);
  float* klp    = (float*)(ws + 525312);
  float* logdet = (float*)(ws + 526336);
  int*   cnt    = (int*)  (ws + 528384);
  int*   idx    = (int*)  (ws + 528392);
  float* sig    = (float*)(ws + 1048576);
  const size_t base = 1048576;

  int ch = 0;
  if      (ws_size >= base + (size_t)256 * 2 * MSZ * 4) ch = 256;
  else if (ws_size >= base + (size_t)64  * 2 * MSZ * 4) ch = 64;
  else if (ws_size >= base + (size_t)16  * 2 * MSZ * 4) ch = 16;
  else if (ws_size >= base + (size_t)4   * 2 * MSZ * 4) ch = 4;
  else if (ws_size >= base + (size_t)1   * 2 * MSZ * 4) ch = 1;
  if (ch == 0){
    k_sentinel<<<1, 1, 0, stream>>>(out);
    return;
  }

  k0_partition<<<1, 512, 0, stream>>>(lab, cnt, idx);
  k1_means<<<256, 1024, 0, stream>>>(mu, lab, cnt, means);
  for (int c0 = 0; c0 < 256; c0 += ch){
    k2_gram<<<ch * 2, 512, 0, stream>>>(mu, cov, means, cnt, idx, sig, c0);
    k3a_chol<<<ch * 2, 512, 0, stream>>>(sig, logdet, c0);
    k3b_trsm<<<ch, 256, 0, stream>>>(sig, trp, c0);
    k3c_quad<<<ch, 64, 0, stream>>>(means, sig, trp, logdet, klp, c0);
  }
  k4_final<<<1, 256, 0, stream>>>(klp, cnt, out);
}

// Round 9
// 1710.355 us; speedup vs baseline: 1.8733x; 1.8733x over previous
//
#include <hip/hip_runtime.h>
#include <cmath>

typedef __attribute__((ext_vector_type(4))) float f32x4;
typedef __attribute__((ext_vector_type(8))) short bf16x8;

// matrices are full 256x256 fp32 squares; strict upper of each L is zeroed
#define MSZ 65536

__device__ __forceinline__ unsigned short f2bf(float f){
  unsigned u = __float_as_uint(f);
  unsigned r = (u + 0x7FFFu + ((u >> 16) & 1u)) >> 16;
  return (unsigned short)r;
}

__device__ __forceinline__ float dot4(f32x4 a, f32x4 b){
  return a.x*b.x + a.y*b.y + a.z*b.z + a.w*b.w;
}

__device__ __forceinline__ void tri_decode(int i, int& R, int& C){
  int Rv = (int)((sqrtf(8.f*(float)i + 1.f) - 1.f) * 0.5f);
  while ((Rv+1)*(Rv+2)/2 <= i) ++Rv;
  while (Rv*(Rv+1)/2 > i) --Rv;
  R = Rv; C = i - Rv*(Rv+1)/2;
}

__global__ void k_sentinel(float* __restrict__ out){ out[0] = 123456.0f; }

// ---------------- K0: partition batch indices by label ----------------
__global__ void k0_partition(const int* __restrict__ lab, int* __restrict__ cnt, int* __restrict__ idx){
  __shared__ int lcnt0[8], lcnt1[8];
  int t = threadIdx.x;              // 512 threads, 8 waves
  int w = t >> 6, lane = t & 63;
  int l = lab[t];
  unsigned long long m0 = __ballot(l == 0);
  unsigned long long bm = (lane == 0) ? 0ull : ((1ull << lane) - 1ull);
  int r0 = __popcll(m0 & bm);
  int r1 = __popcll((~m0) & bm);
  if (lane == 0){ lcnt0[w] = __popcll(m0); lcnt1[w] = 64 - __popcll(m0); }
  __syncthreads();
  int base0 = 0, base1 = 0, n0 = 0;
  #pragma unroll
  for (int i = 0; i < 8; ++i){
    if (i < w){ base0 += lcnt0[i]; base1 += lcnt1[i]; }
    n0 += lcnt0[i];
  }
  int pos = (l == 0) ? (base0 + r0) : (n0 + base1 + r1);
  idx[pos] = t;
  if (t == 0){ cnt[0] = n0; cnt[1] = 512 - n0; }
}

// ---------------- K1: per-label means ----------------
__global__ __launch_bounds__(1024) void k1_means(const float* __restrict__ x, const int* __restrict__ lab,
                                                 const int* __restrict__ cnt, float* __restrict__ means){
  __shared__ int labs[512];
  __shared__ float part[8][256];
  int t = threadIdx.x, c = blockIdx.x;
  if (t < 512) labs[t] = lab[t];
  __syncthreads();
  int k = t & 255, bq = t >> 8;
  float s0 = 0.f, s1 = 0.f;
  const float* xc = x + (size_t)c * 256 + k;
  for (int b = bq; b < 512; b += 4){
    float v = xc[(size_t)b * 65536];
    if (labs[b] == 0) s0 += v; else s1 += v;
  }
  part[bq*2+0][k] = s0;
  part[bq*2+1][k] = s1;
  __syncthreads();
  if (t < 256){
    float m0 = part[0][t] + part[2][t] + part[4][t] + part[6][t];
    float m1 = part[1][t] + part[3][t] + part[5][t] + part[7][t];
    float n0 = (float)cnt[0], n1 = (float)cnt[1];
    means[(size_t)c * 256 + t]         = m0 / fmaxf(n0, 1.f);
    means[(size_t)(256 + c) * 256 + t] = m1 / fmaxf(n1, 1.f);
  }
}

// ---------------- K2: per-(channel,label) Gram via MFMA -> Sigma full square, upper zeroed ----------------
__global__ __launch_bounds__(512) void k2_gram(const float* __restrict__ x, const float* __restrict__ cov,
    const float* __restrict__ means, const int* __restrict__ cnt, const int* __restrict__ idx,
    float* __restrict__ sig, int c0){
  __shared__ uint4 XT4[1280];      // 256 k-rows x (4 uint4 data + 1 pad uint4)
  __shared__ float mlds[256];
  int t = threadIdx.x;
  int bid = blockIdx.x;
  int l = bid & 1, c = c0 + (bid >> 1);
  int n0 = cnt[0], n1 = cnt[1];
  int n = l ? n1 : n0;
  int start = l ? n0 : 0;
  if (t < 256) mlds[t] = means[(size_t)(l * 256 + c) * 256 + t];

  f32x4 acc[8][4];
  #pragma unroll
  for (int i = 0; i < 8; ++i)
    #pragma unroll
    for (int jn = 0; jn < 4; ++jn){ f32x4 z; z.x = 0.f; z.y = 0.f; z.z = 0.f; z.w = 0.f; acc[i][jn] = z; }

  int lane = t & 63, wav = t >> 6;
  int wr = wav >> 2, wc = wav & 3;
  int lrow = lane & 15, lhalf = lane >> 4;   // lhalf in [0,4)
  int kq = t & 255, bh = t >> 8;
  int nst = (n + 31) >> 5;

  for (int s = 0; s < nst; ++s){
    __syncthreads();
    unsigned pk[8];
    #pragma unroll
    for (int m = 0; m < 8; ++m){
      int b0 = s * 32 + bh * 16 + 2 * m;
      float v0 = 0.f, v1 = 0.f;
      if (b0 < n)     v0 = x[((size_t)idx[start + b0] * 256 + c) * 256 + kq];
      if (b0 + 1 < n) v1 = x[((size_t)idx[start + b0 + 1] * 256 + c) * 256 + kq];
      pk[m] = (unsigned)f2bf(v0) | ((unsigned)f2bf(v1) << 16);
    }
    XT4[kq * 5 + bh * 2 + 0] = make_uint4(pk[0], pk[1], pk[2], pk[3]);
    XT4[kq * 5 + bh * 2 + 1] = make_uint4(pk[4], pk[5], pk[6], pk[7]);
    __syncthreads();
    bf16x8 af[8], bfr[4];
    #pragma unroll
    for (int i = 0; i < 8; ++i){
      int T = wr * 8 + i;
      af[i] = *reinterpret_cast<const bf16x8*>(&XT4[(T * 16 + lrow) * 5 + lhalf]);
    }
    #pragma unroll
    for (int jn = 0; jn < 4; ++jn){
      int T = wc * 4 + jn;
      bfr[jn] = *reinterpret_cast<const bf16x8*>(&XT4[(T * 16 + lrow) * 5 + lhalf]);
    }
    #pragma unroll
    for (int i = 0; i < 8; ++i)
      #pragma unroll
      for (int jn = 0; jn < 4; ++jn)
        acc[i][jn] = __builtin_amdgcn_mfma_f32_16x16x32_bf16(af[i], bfr[jn], acc[i][jn], 0, 0, 0);
  }
  __syncthreads();

  float invn = 1.0f / fmaxf((float)n, 1.0f);
  float* sigm = sig + (size_t)bid * MSZ;
  #pragma unroll
  for (int i = 0; i < 8; ++i){
    int Rb = (wr * 8 + i) * 16 + lhalf * 4;
    #pragma unroll
    for (int jn = 0; jn < 4; ++jn){
      int Cc = (wc * 4 + jn) * 16 + lrow;
      #pragma unroll
      for (int r = 0; r < 4; ++r){
        int R = Rb + r;
        float v = acc[i][jn][r] * invn + cov[R * 256 + Cc] - mlds[R] * mlds[Cc];
        sigm[R * 256 + Cc] = (Cc <= R) ? v : 0.0f;   // zero strict upper
      }
    }
  }
}

// ---------------- K3a helper: in-LDS 128x128 right-looking Cholesky ----------------
// LB: 128 x (stride 132). Ldall[kb*1152 + q*36 + j] = Linv_kb[j][q] (dense, zeros where q>j).
__device__ void factor128_lds(float* __restrict__ LB, float* __restrict__ Ldall,
                              int t, float& ldacc){
  for (int kb = 0; kb < 4; ++kb){
    int j0 = kb * 32;
    float* Ld = Ldall + kb * 1152;
    // ---- wave0: lockstep chol of 32x32 diag (r4/r6/r8-verified) + explicit inverse
    if (t < 32){
      for (int jj = 0; jj < 32; ++jj){
        float dv = sqrtf(LB[(j0+jj)*132 + j0+jj]);
        float inv = 1.0f / dv;
        if (t == jj){ LB[(j0+jj)*132 + j0+jj] = dv; ldacc += logf(dv); }
        if (t > jj){
          float lv = LB[(j0+t)*132 + j0+jj] * inv;
          LB[(j0+t)*132 + j0+jj] = lv;
          for (int cq = jj+1; cq <= t; ++cq)
            LB[(j0+t)*132 + j0+cq] -= lv * LB[(j0+cq)*132 + j0+jj];
        }
      }
      // lane j: Linv column j -> Ld row q=j  (Ld[j*36 + i] = Linv[i][j])
      int j = t;
      for (int i = 0; i < j; ++i) Ld[j*36 + i] = 0.f;
      float xjj = 1.0f / LB[(j0+j)*132 + j0+j];
      Ld[j*36 + j] = xjj;
      for (int i = j+1; i < 32; ++i){
        float s = 0.f;
        for (int p = j; p < i; ++p)
          s += LB[(j0+i)*132 + j0+p] * Ld[j*36 + p];
        Ld[j*36 + i] = -s / LB[(j0+i)*132 + j0+i];
      }
    }
    __syncthreads();
    int nr = 96 - j0;              // panel rows below diag
    if (nr > 0){
      // ---- panel: W = A * Linv^T (parallel GEMM, register-staged, in place)
      bool act = (t < nr * 4);
      int row = j0 + 32 + (t >> 2);
      int g = t & 3;
      if (row > 127) row = 127;
      f32x4 a[8]; float w[8];
      if (act){
        #pragma unroll
        for (int q = 0; q < 8; ++q) a[q] = *(const f32x4*)&LB[row*132 + j0 + 4*q];
        #pragma unroll
        for (int jl = 0; jl < 8; ++jl){
          int j = 8*g + jl;
          float s = 0.f;
          #pragma unroll
          for (int q = 0; q < 8; ++q){
            s += a[q].x * Ld[(4*q+0)*36 + j];
            s += a[q].y * Ld[(4*q+1)*36 + j];
            s += a[q].z * Ld[(4*q+2)*36 + j];
            s += a[q].w * Ld[(4*q+3)*36 + j];
          }
          w[jl] = s;
        }
      }
      __syncthreads();
      if (act){
        #pragma unroll
        for (int jl = 0; jl < 8; ++jl)
          LB[row*132 + j0 + 8*g + jl] = w[jl];
      }
      __syncthreads();
      // ---- trailing rank-32 update: 4x4 tiles over lower tile-triangle, LDS RMW
      int nt = nr >> 2;
      int Tt = nt*(nt+1)/2;        // 300 / 136 / 36
      if (t < Tt){
        int R, C; tri_decode(t, R, C);
        int rb = j0+32+4*R, cb = j0+32+4*C;
        float s[16];
        #pragma unroll
        for (int q = 0; q < 16; ++q) s[q] = 0.f;
        #pragma unroll 4
        for (int qc = 0; qc < 8; ++qc){
          f32x4 a0 = *(const f32x4*)&LB[(rb+0)*132 + j0 + 4*qc];
          f32x4 a1 = *(const f32x4*)&LB[(rb+1)*132 + j0 + 4*qc];
          f32x4 a2 = *(const f32x4*)&LB[(rb+2)*132 + j0 + 4*qc];
          f32x4 a3 = *(const f32x4*)&LB[(rb+3)*132 + j0 + 4*qc];
          f32x4 b0 = *(const f32x4*)&LB[(cb+0)*132 + j0 + 4*qc];
          f32x4 b1 = *(const f32x4*)&LB[(cb+1)*132 + j0 + 4*qc];
          f32x4 b2 = *(const f32x4*)&LB[(cb+2)*132 + j0 + 4*qc];
          f32x4 b3 = *(const f32x4*)&LB[(cb+3)*132 + j0 + 4*qc];
          s[0]+=dot4(a0,b0);  s[1]+=dot4(a0,b1);  s[2]+=dot4(a0,b2);  s[3]+=dot4(a0,b3);
          s[4]+=dot4(a1,b0);  s[5]+=dot4(a1,b1);  s[6]+=dot4(a1,b2);  s[7]+=dot4(a1,b3);
          s[8]+=dot4(a2,b0);  s[9]+=dot4(a2,b1);  s[10]+=dot4(a2,b2); s[11]+=dot4(a2,b3);
          s[12]+=dot4(a3,b0); s[13]+=dot4(a3,b1); s[14]+=dot4(a3,b2); s[15]+=dot4(a3,b3);
        }
        #pragma unroll
        for (int i2 = 0; i2 < 4; ++i2)
          #pragma unroll
          for (int jl = 0; jl < 4; ++jl)
            LB[(rb+i2)*132 + cb+jl] -= s[i2*4+jl];
      }
    }
    __syncthreads();
  }
}

// ---------------- K3a: two-level Schur Cholesky, all working state in LDS ----------------
// P1 chol(A11) in LDS; P2 TRSM L21=A21*L11^-T (W in same LDS buffer); P3 SYRK streamed
// from global into regs vs LDS L21, deposited back to LDS; P4 chol(A22') in LDS.
__global__ __launch_bounds__(512) void k3a_chol(float* __restrict__ sig, float* __restrict__ logdet, int c0){
  extern __shared__ float smem[];
  float* LB    = smem;                 // 128*132 = 16896 floats
  float* Ldall = smem + 16896;         // 4*1152  = 4608
  float* LoffT = smem + 21504;         // 6*1152  = 6912   (total 28416 floats = 113664 B)
  int t = threadIdx.x;
  int bid = blockIdx.x;
  int l = bid & 1, c = c0 + (bid >> 1);
  float* A = sig + (size_t)bid * MSZ;
  float ldacc = 0.f;

  // ==== P1: load A11, factor in LDS ====
  for (int i = t; i < 4096; i += 512){
    int r = i >> 5, q = i & 31;
    *(f32x4*)&LB[r*132 + 4*q] = *(const f32x4*)&A[(size_t)r*256 + 4*q];
  }
  __syncthreads();
  factor128_lds(LB, Ldall, t, ldacc);
  // extract L11 strictly-lower 32x32 blocks (transposed) for P2's GEMMs
  {
    for (int i = t; i < 6144; i += 512){
      int idx = i >> 10, rem = i & 1023, j = rem >> 5, q = rem & 31;
      int kb = (idx < 1) ? 1 : ((idx < 3) ? 2 : 3);
      int p  = (idx == 0) ? 0 : ((idx < 3) ? (idx - 1) : (idx - 3));
      LoffT[idx*1152 + q*36 + j] = LB[(32*kb + j)*132 + 32*p + q];
    }
  }
  // write L11 (mask junk above diag to zero)
  for (int i = t; i < 4096; i += 512){
    int r = i >> 5, q = i & 31;
    f32x4 v = *(const f32x4*)&LB[r*132 + 4*q];
    int cb = 4*q;
    v.x = (cb+0 <= r) ? v.x : 0.f;
    v.y = (cb+1 <= r) ? v.y : 0.f;
    v.z = (cb+2 <= r) ? v.z : 0.f;
    v.w = (cb+3 <= r) ? v.w : 0.f;
    *(f32x4*)&A[(size_t)r*256 + 4*q] = v;
  }
  __syncthreads();

  // ==== P2: TRSM L21 = A21 * L11^-T; W lives in LB ====
  {
    int r = t >> 2, g = t & 3;    // 128 rows x 4 col-groups, all 512 threads active
    for (int kb = 0; kb < 4; ++kb){
      f32x4 v0 = *(const f32x4*)&A[(size_t)(128+r)*256 + 32*kb + 8*g];
      f32x4 v1 = *(const f32x4*)&A[(size_t)(128+r)*256 + 32*kb + 8*g + 4];
      float accv[8] = {v0.x, v0.y, v0.z, v0.w, v1.x, v1.y, v1.z, v1.w};
      for (int p = 0; p < kb; ++p){
        int idx = kb*(kb-1)/2 + p;
        const float* LT = &LoffT[idx*1152];
        f32x4 wv[8];
        #pragma unroll
        for (int q = 0; q < 8; ++q) wv[q] = *(const f32x4*)&LB[r*132 + 32*p + 4*q];
        #pragma unroll
        for (int q4 = 0; q4 < 8; ++q4){
          #pragma unroll
          for (int jl = 0; jl < 8; ++jl){
            float lt0 = LT[(4*q4+0)*36 + 8*g+jl];
            float lt1 = LT[(4*q4+1)*36 + 8*g+jl];
            float lt2 = LT[(4*q4+2)*36 + 8*g+jl];
            float lt3 = LT[(4*q4+3)*36 + 8*g+jl];
            accv[jl] -= wv[q4].x*lt0 + wv[q4].y*lt1 + wv[q4].z*lt2 + wv[q4].w*lt3;
          }
        }
      }
      #pragma unroll
      for (int jl = 0; jl < 8; ++jl) LB[r*132 + 32*kb + 8*g + jl] = accv[jl];
      __syncthreads();
      f32x4 vv[8];
      #pragma unroll
      for (int q = 0; q < 8; ++q) vv[q] = *(const f32x4*)&LB[r*132 + 32*kb + 4*q];
      __syncthreads();
      const float* Ld = &Ldall[kb*1152];
      #pragma unroll
      for (int jl = 0; jl < 8; ++jl){
        int j = 8*g + jl;
        float s = 0.f;
        #pragma unroll
        for (int q = 0; q < 8; ++q){
          s += vv[q].x * Ld[(4*q+0)*36 + j];
          s += vv[q].y * Ld[(4*q+1)*36 + j];
          s += vv[q].z * Ld[(4*q+2)*36 + j];
          s += vv[q].w * Ld[(4*q+3)*36 + j];
        }
        LB[r*132 + 32*kb + 8*g + jl] = s;
      }
      __syncthreads();
    }
    // write L21 (dense)
    for (int i = t; i < 4096; i += 512){
      int rr = i >> 5, q = i & 31;
      *(f32x4*)&A[(size_t)(128+rr)*256 + 4*q] = *(const f32x4*)&LB[rr*132 + 4*q];
    }
  }

  // ==== P3: SYRK A22' = A22 - L21*L21^T (stream A22, dots vs LDS L21, hold in regs) ====
  float s1[16], s2[16];
  int R1 = 0, C1 = 0, R2 = 0, C2 = 0;
  bool v1 = (t < 528), v2 = (t < 16);
  if (v1) tri_decode(t, R1, C1);
  if (v2) tri_decode(512 + t, R2, C2);
  #pragma unroll
  for (int q = 0; q < 16; ++q){ s1[q] = 0.f; s2[q] = 0.f; }
  if (v1){
    for (int qc = 0; qc < 32; ++qc){
      f32x4 a0 = *(const f32x4*)&LB[(4*R1+0)*132 + 4*qc];
      f32x4 a1 = *(const f32x4*)&LB[(4*R1+1)*132 + 4*qc];
      f32x4 a2 = *(const f32x4*)&LB[(4*R1+2)*132 + 4*qc];
      f32x4 a3 = *(const f32x4*)&LB[(4*R1+3)*132 + 4*qc];
      f32x4 b0 = *(const f32x4*)&LB[(4*C1+0)*132 + 4*qc];
      f32x4 b1 = *(const f32x4*)&LB[(4*C1+1)*132 + 4*qc];
      f32x4 b2 = *(const f32x4*)&LB[(4*C1+2)*132 + 4*qc];
      f32x4 b3 = *(const f32x4*)&LB[(4*C1+3)*132 + 4*qc];
      s1[0]+=dot4(a0,b0);  s1[1]+=dot4(a0,b1);  s1[2]+=dot4(a0,b2);  s1[3]+=dot4(a0,b3);
      s1[4]+=dot4(a1,b0);  s1[5]+=dot4(a1,b1);  s1[6]+=dot4(a1,b2);  s1[7]+=dot4(a1,b3);
      s1[8]+=dot4(a2,b0);  s1[9]+=dot4(a2,b1);  s1[10]+=dot4(a2,b2); s1[11]+=dot4(a2,b3);
      s1[12]+=dot4(a3,b0); s1[13]+=dot4(a3,b1); s1[14]+=dot4(a3,b2); s1[15]+=dot4(a3,b3);
    }
    #pragma unroll
    for (int i2 = 0; i2 < 4; ++i2){
      f32x4 av = *(const f32x4*)&A[(size_t)(128+4*R1+i2)*256 + 128 + 4*C1];
      s1[i2*4+0] = av.x - s1[i2*4+0];
      s1[i2*4+1] = av.y - s1[i2*4+1];
      s1[i2*4+2] = av.z - s1[i2*4+2];
      s1[i2*4+3] = av.w - s1[i2*4+3];
    }
  }
  if (v2){
    for (int qc = 0; qc < 32; ++qc){
      f32x4 a0 = *(const f32x4*)&LB[(4*R2+0)*132 + 4*qc];
      f32x4 a1 = *(const f32x4*)&LB[(4*R2+1)*132 + 4*qc];
      f32x4 a2 = *(const f32x4*)&LB[(4*R2+2)*132 + 4*qc];
      f32x4 a3 = *(const f32x4*)&LB[(4*R2+3)*132 + 4*qc];
      f32x4 b0 = *(const f32x4*)&LB[(4*C2+0)*132 + 4*qc];
      f32x4 b1 = *(const f32x4*)&LB[(4*C2+1)*132 + 4*qc];
      f32x4 b2 = *(const f32x4*)&LB[(4*C2+2)*132 + 4*qc];
      f32x4 b3 = *(const f32x4*)&LB[(4*C2+3)*132 + 4*qc];
      s2[0]+=dot4(a0,b0);  s2[1]+=dot4(a0,b1);  s2[2]+=dot4(a0,b2);  s2[3]+=dot4(a0,b3);
      s2[4]+=dot4(a1,b0);  s2[5]+=dot4(a1,b1);  s2[6]+=dot4(a1,b2);  s2[7]+=dot4(a1,b3);
      s2[8]+=dot4(a2,b0);  s2[9]+=dot4(a2,b1);  s2[10]+=dot4(a2,b2); s2[11]+=dot4(a2,b3);
      s2[12]+=dot4(a3,b0); s2[13]+=dot4(a3,b1); s2[14]+=dot4(a3,b2); s2[15]+=dot4(a3,b3);
    }
    #pragma unroll
    for (int i2 = 0; i2 < 4; ++i2){
      f32x4 av = *(const f32x4*)&A[(size_t)(128+4*R2+i2)*256 + 128 + 4*C2];
      s2[i2*4+0] = av.x - s2[i2*4+0];
      s2[i2*4+1] = av.y - s2[i2*4+1];
      s2[i2*4+2] = av.z - s2[i2*4+2];
      s2[i2*4+3] = av.w - s2[i2*4+3];
    }
  }
  __syncthreads();     // all reads of LB (L21) complete
  if (v1){
    #pragma unroll
    for (int i2 = 0; i2 < 4; ++i2)
      #pragma unroll
      for (int jl = 0; jl < 4; ++jl)
        LB[(4*R1+i2)*132 + 4*C1+jl] = s1[i2*4+jl];
  }
  if (v2){
    #pragma unroll
    for (int i2 = 0; i2 < 4; ++i2)
      #pragma unroll
      for (int jl = 0; jl < 4; ++jl)
        LB[(4*R2+i2)*132 + 4*C2+jl] = s2[i2*4+jl];
  }
  __syncthreads();

  // ==== P4: factor A22' in LDS; write L22 ====
  factor128_lds(LB, Ldall, t, ldacc);
  for (int i = t; i < 4096; i += 512){
    int r = i >> 5, q = i & 31;
    f32x4 v = *(const f32x4*)&LB[r*132 + 4*q];
    int cb = 4*q;
    v.x = (cb+0 <= r) ? v.x : 0.f;
    v.y = (cb+1 <= r) ? v.y : 0.f;
    v.z = (cb+2 <= r) ? v.z : 0.f;
    v.w = (cb+3 <= r) ? v.w : 0.f;
    *(f32x4*)&A[(size_t)(128+r)*256 + 128 + 4*q] = v;
  }
  // logdet: reduce wave0 lanes' per-column partials
  if (t < 32){
    float v = ldacc;
    #pragma unroll
    for (int m = 1; m < 32; m <<= 1) v += __shfl_xor(v, m);
    if (t == 0) logdet[l * 256 + c] = 2.0f * v;
  }
}

// ---------------- K3b: TRSM L1 W = L0 in place, column-per-thread; trp = ||W||_F^2 ----------------
__global__ __launch_bounds__(256) void k3b_trsm(float* __restrict__ sig, float* __restrict__ trp, int c0){
  __shared__ float L1blk[32 * 256];   // 32 KB
  __shared__ float redw[4];
  int t = threadIdx.x, b = blockIdx.x;
  int lane = t & 63, wav = t >> 6;
  const float* L1 = sig + (size_t)(b * 2 + 1) * MSZ;
  float* W = sig + (size_t)(b * 2) * MSZ;     // starts as L0, becomes W
  float tracc = 0.f;

  for (int RB = 0; RB < 8; ++RB){
    int r0 = RB * 32;
    __syncthreads();
    for (int i = t; i < 32 * 256; i += 256)
      L1blk[i] = L1[(size_t)(r0 + (i >> 8)) * 256 + (i & 255)];
    __syncthreads();

    float acc[32];
    #pragma unroll
    for (int r = 0; r < 32; ++r) acc[r] = W[(size_t)(r0 + r) * 256 + t];

    for (int p = 0; p < r0; p += 8){
      float wv[8];
      #pragma unroll
      for (int q = 0; q < 8; ++q) wv[q] = W[(size_t)(p + q) * 256 + t];
      #pragma unroll
      for (int r = 0; r < 32; ++r){
        const f32x4 La = *(const f32x4*)&L1blk[r * 256 + p];
        const f32x4 Lb = *(const f32x4*)&L1blk[r * 256 + p + 4];
        acc[r] -= La.x * wv[0] + La.y * wv[1] + La.z * wv[2] + La.w * wv[3]
                + Lb.x * wv[4] + Lb.y * wv[5] + Lb.z * wv[6] + Lb.w * wv[7];
      }
    }
    // in-block forward substitution (column-private, no barriers)
    #pragma unroll
    for (int rr = 0; rr < 32; ++rr){
      float v = acc[rr];
      #pragma unroll
      for (int q = 0; q < rr; ++q)
        v -= L1blk[rr * 256 + r0 + q] * acc[q];
      v /= L1blk[rr * 256 + r0 + rr];
      acc[rr] = v;
      tracc += v * v;
      W[(size_t)(r0 + rr) * 256 + t] = v;
    }
  }
  #pragma unroll
  for (int m = 1; m < 64; m <<= 1) tracc += __shfl_xor(tracc, m);
  if (lane == 0) redw[wav] = tracc;
  __syncthreads();
  if (t == 0) trp[c0 + b] = redw[0] + redw[1] + redw[2] + redw[3];
}

// ---------------- K3c: quad = ||L1^-1 d||^2; final per-channel kl ----------------
__global__ __launch_bounds__(64) void k3c_quad(const float* __restrict__ means, const float* __restrict__ sig,
    const float* __restrict__ trp, const float* __restrict__ logdet, float* __restrict__ klp, int c0){
  __shared__ float y[256];
  int t = threadIdx.x, b = blockIdx.x;
  int c = c0 + b;
  const float* L1 = sig + (size_t)(b * 2 + 1) * MSZ;
  const float* m1p = means + (size_t)(256 + c) * 256;
  const float* m0p = means + (size_t)c * 256;

  for (int r = 0; r < 256; ++r){
    float part = 0.f;
    for (int p = t; p < r; p += 64)
      part += L1[(size_t)r * 256 + p] * y[p];
    #pragma unroll
    for (int m = 1; m < 64; m <<= 1) part += __shfl_xor(part, m);
    if (t == 0)
      y[r] = ((m1p[r] - m0p[r]) - part) / L1[(size_t)r * 256 + r];
    __syncthreads();
  }
  float q = 0.f;
  #pragma unroll
  for (int i = 0; i < 4; ++i){ float v = y[t + 64 * i]; q += v * v; }
  #pragma unroll
  for (int m = 1; m < 64; m <<= 1) q += __shfl_xor(q, m);
  if (t == 0)
    klp[c] = 0.5f * (trp[c] + q - 256.0f + logdet[256 + c] - logdet[c]);
}

// ---------------- K4: final reduce + scale ----------------
__global__ void k4_final(const float* __restrict__ klp, const int* __restrict__ cnt, float* __restrict__ out){
  __shared__ float red[256];
  int t = threadIdx.x;
  red[t] = klp[t];
  __syncthreads();
  for (int s = 128; s > 0; s >>= 1){
    if (t < s) red[t] += red[t + s];
    __syncthreads();
  }
  if (t == 0){
    float n0 = (float)cnt[0], n1 = (float)cnt[1];
    out[0] = red[0] * n0 * n1 / 256.0f / 512.0f / 512.0f;
  }
}

extern "C" void kernel_launch(void* const* d_in, const int* in_sizes, int n_in,
                              void* d_out, int out_size, void* d_ws, size_t ws_size,
                              hipStream_t stream){
  (void)in_sizes; (void)n_in; (void)out_size;
  const float* mu  = (const float*)d_in[0];
  const float* cov = (const float*)d_in[1];
  const int*   lab = (const int*)d_in[2];
  float* out = (float*)d_out;
  char* ws = (char*)d_ws;
  // ws layout (bytes):
  // means  @ 0        (524288)   trp @ 524288 (1024)   klp @ 525312 (1024)
  // logdet @ 526336   (2048)     cnt @ 528384 (8)      idx @ 528392 (2048)
  // sig    @ 1048576  (ch*2 full 256x256 fp32 squares)
  float* means  = (float*)ws;
  float* trp    = (float*)(ws + 524288);
  float* klp    = (float*)(ws + 525312);
  float* logdet = (float*)(ws + 526336);
  int*   cnt    = (int*)  (ws + 528384);
  int*   idx    = (int*)  (ws + 528392);
  float* sig    = (float*)(ws + 1048576);
  const size_t base = 1048576;

  int ch = 0;
  if      (ws_size >= base + (size_t)256 * 2 * MSZ * 4) ch = 256;
  else if (ws_size >= base + (size_t)64  * 2 * MSZ * 4) ch = 64;
  else if (ws_size >= base + (size_t)16  * 2 * MSZ * 4) ch = 16;
  else if (ws_size >= base + (size_t)4   * 2 * MSZ * 4) ch = 4;
  else if (ws_size >= base + (size_t)1   * 2 * MSZ * 4) ch = 1;
  if (ch == 0){
    k_sentinel<<<1, 1, 0, stream>>>(out);
    return;
  }

  const int k3a_lds = 28416 * 4;   // 113664 B dynamic LDS
  (void)hipFuncSetAttribute((const void*)k3a_chol,
                            hipFuncAttributeMaxDynamicSharedMemorySize, k3a_lds);

  k0_partition<<<1, 512, 0, stream>>>(lab, cnt, idx);
  k1_means<<<256, 1024, 0, stream>>>(mu, lab, cnt, means);
  for (int c0 = 0; c0 < 256; c0 += ch){
    k2_gram<<<ch * 2, 512, 0, stream>>>(mu, cov, means, cnt, idx, sig, c0);
    k3a_chol<<<ch * 2, 512, k3a_lds, stream>>>(sig, logdet, c0);
    k3b_trsm<<<ch, 256, 0, stream>>>(sig, trp, c0);
    k3c_quad<<<ch, 64, 0, stream>>>(means, sig, trp, logdet, klp, c0);
  }
  k4_final<<<1, 256, 0, stream>>>(klp, cnt, out);
}